// Round 1
// baseline (437.068 us; speedup 1.0000x reference)
//
#include <hip/hip_runtime.h>

#pragma clang fp contract(off)

#define BB 32
#define NN 8192
#define GG 256
#define KK 32

// ---------------- FPS: one block per batch ----------------
__global__ __launch_bounds__(1024, 4) void fps_kernel(const float* __restrict__ xyz,
                                                      float* __restrict__ out) {
#pragma clang fp contract(off)
  const int b = blockIdx.x;
  const int t = threadIdx.x;
  const int lane = t & 63;
  const int wave = t >> 6;
  const float* __restrict__ P = xyz + (size_t)b * NN * 3;

  float px[8], py[8], pz[8], md[8];
#pragma unroll
  for (int j = 0; j < 8; ++j) {
    const int idx = t + j * 1024;
    px[j] = P[idx * 3 + 0];
    py[j] = P[idx * 3 + 1];
    pz[j] = P[idx * 3 + 2];
    md[j] = __builtin_inff();
  }

  __shared__ unsigned long long warr[2][16];
  float* __restrict__ cout = out + (size_t)BB * GG * KK * 3;

  unsigned win = 0;  // first center is index 0 (scan emits initial carry)
  for (int i = 0; i < GG; ++i) {
    // broadcast load of current center coords (uniform address -> L1/L2 hit)
    const float cx = P[win * 3 + 0];
    const float cy = P[win * 3 + 1];
    const float cz = P[win * 3 + 2];
    if (t == 0) {
      float* co = cout + ((size_t)b * GG + i) * 3;
      co[0] = cx; co[1] = cy; co[2] = cz;
    }
    if (i == GG - 1) break;

    // update running min distance, track local argmax (lowest index on ties)
    float bestv = -1.0f;
    unsigned besti = 0;
#pragma unroll
    for (int j = 0; j < 8; ++j) {
      const float dx = px[j] - cx;
      const float dy = py[j] - cy;
      const float dz = pz[j] - cz;
      const float d = dx * dx + dy * dy + dz * dz;   // ((dx2+dy2)+dz2), no FMA
      const float m = md[j] < d ? md[j] : d;
      md[j] = m;
      if (m > bestv) { bestv = m; besti = (unsigned)(t + j * 1024); }
    }

    // wave max-reduce: key = (f32 bits << 32) | ~idx  (ties -> smaller idx)
    unsigned long long key =
        ((unsigned long long)__float_as_uint(bestv) << 32) | (unsigned)(~besti);
#pragma unroll
    for (int s = 32; s > 0; s >>= 1) {
      const unsigned long long o = __shfl_xor(key, s, 64);
      key = o > key ? o : key;
    }
    if (lane == 0) warr[i & 1][wave] = key;
    __syncthreads();
    // every wave reduces the 16 per-wave keys (double-buffered -> 1 barrier/iter)
    unsigned long long k2 = warr[i & 1][lane & 15];
#pragma unroll
    for (int s = 8; s > 0; s >>= 1) {
      const unsigned long long o = __shfl_xor(k2, s, 64);
      k2 = o > k2 ? o : k2;
    }
    win = ~(unsigned)(k2 & 0xFFFFFFFFull);
  }
}

// ---------------- KNN + gather: 8 blocks per batch ----------------
__global__ __launch_bounds__(512, 2) void knn_kernel(const float* __restrict__ xyz,
                                                     float* __restrict__ out) {
#pragma clang fp contract(off)
  const int b = blockIdx.x >> 3;
  const int chunk = blockIdx.x & 7;
  const int t = threadIdx.x;
  const int lane = t & 63;
  const int wave = t >> 6;
  const float* __restrict__ P = xyz + (size_t)b * NN * 3;

  __shared__ float xs[NN], ys[NN], zs[NN];          // 96 KB SoA planes
  __shared__ unsigned long long cand[8][256];       // 16 KB per-wave candidates

  for (int pt = t; pt < NN; pt += 512) {
    xs[pt] = P[pt * 3 + 0];
    ys[pt] = P[pt * 3 + 1];
    zs[pt] = P[pt * 3 + 2];
  }
  __syncthreads();

  const float* __restrict__ cent = out + (size_t)BB * GG * KK * 3;

  for (int gi = 0; gi < 4; ++gi) {
    const int g = chunk * 32 + wave * 4 + gi;
    const float cx = cent[((size_t)b * GG + g) * 3 + 0];
    const float cy = cent[((size_t)b * GG + g) * 3 + 1];
    const float cz = cent[((size_t)b * GG + g) * 3 + 2];

    // Phase A: 128 squared distances per lane, kept in registers
    float d2r[128];
    float mn = __builtin_inff();
#pragma unroll
    for (int j = 0; j < 128; ++j) {
      const int idx = lane + j * 64;
      const float dx = xs[idx] - cx;
      const float dy = ys[idx] - cy;
      const float dz = zs[idx] - cz;
      const float d2 = dx * dx + dy * dy + dz * dz;  // no FMA
      d2r[j] = d2;
      mn = fminf(mn, d2);
    }

    // threshold v = 32nd-smallest of the 64 per-lane minima (bitonic sort)
    float sm = mn;
#pragma unroll
    for (int k = 2; k <= 64; k <<= 1) {
#pragma unroll
      for (int j2 = k >> 1; j2 > 0; j2 >>= 1) {
        const float o = __shfl_xor(sm, j2, 64);
        const bool keepMin = (((lane & k) == 0) == ((lane & j2) == 0));
        sm = keepMin ? fminf(sm, o) : fmaxf(sm, o);
      }
    }
    const float v = __shfl(sm, 31, 64);
    const float vi = __uint_as_float(__float_as_uint(v) + 8);  // +8 ulp guard

    // Phase B: ballot-compact candidates (d2 <= vi) into LDS
    unsigned cnt = 0;
    unsigned long long* __restrict__ cb = cand[wave];
#pragma unroll
    for (int j = 0; j < 128; ++j) {
      const bool p = d2r[j] <= vi;
      const unsigned long long mk = __ballot(p);
      if (p) {
        const unsigned off = cnt + (unsigned)__popcll(mk & ((1ull << lane) - 1));
        if (off < 256)
          cb[off] = ((unsigned long long)__float_as_uint(d2r[j]) << 32) |
                    (unsigned)(lane + j * 64);
      }
      cnt += (unsigned)__popcll(mk);
    }
    if (cnt > 256) cnt = 256;

    // Phase C: exact sort by (sqrtf(d2) float, idx) ascending
    auto conv = [](unsigned long long e) -> unsigned long long {
      const float d = sqrtf(__uint_as_float((unsigned)(e >> 32)));
      return ((unsigned long long)__float_as_uint(d) << 32) | (e & 0xFFFFFFFFull);
    };

    unsigned long long myk;
    if (cnt <= 64) {
      unsigned long long key = ~0ull;
      if ((unsigned)lane < cnt) key = conv(cb[lane]);
#pragma unroll
      for (int k = 2; k <= 64; k <<= 1) {
#pragma unroll
        for (int j2 = k >> 1; j2 > 0; j2 >>= 1) {
          const unsigned long long o = __shfl_xor(key, j2, 64);
          const bool keepMin = (((lane & k) == 0) == ((lane & j2) == 0));
          const unsigned long long lo = o < key ? o : key;
          const unsigned long long hi = o < key ? key : o;
          key = keepMin ? lo : hi;
        }
      }
      myk = key;
    } else {
      // rare fallback: up to 256 candidates, 32 rounds of wave-argmin
      unsigned long long k0 = ~0ull, k1 = ~0ull, k2 = ~0ull, k3 = ~0ull;
      if ((unsigned)lane < cnt)        k0 = conv(cb[lane]);
      if ((unsigned)(lane + 64) < cnt)  k1 = conv(cb[lane + 64]);
      if ((unsigned)(lane + 128) < cnt) k2 = conv(cb[lane + 128]);
      if ((unsigned)(lane + 192) < cnt) k3 = conv(cb[lane + 192]);
      unsigned long long got = ~0ull;
      for (int r = 0; r < 32; ++r) {
        unsigned long long m01 = k0 < k1 ? k0 : k1;
        unsigned long long m23 = k2 < k3 ? k2 : k3;
        unsigned long long m = m01 < m23 ? m01 : m23;
#pragma unroll
        for (int s = 32; s > 0; s >>= 1) {
          const unsigned long long o = __shfl_xor(m, s, 64);
          m = o < m ? o : m;
        }
        if (lane == r) got = m;
        if (k0 == m) k0 = ~0ull;
        else if (k1 == m) k1 = ~0ull;
        else if (k2 == m) k2 = ~0ull;
        else if (k3 == m) k3 = ~0ull;
      }
      myk = got;
    }

    // gather + recenter + store (lane = rank)
    if (lane < KK) {
      const unsigned idx = (unsigned)(myk & 0xFFFFFFFFull);
      const float ox = xs[idx] - cx;
      const float oy = ys[idx] - cy;
      const float oz = zs[idx] - cz;
      float* __restrict__ po = out + ((size_t)(((size_t)b * GG + g) * KK + lane)) * 3;
      po[0] = ox; po[1] = oy; po[2] = oz;
    }
  }
}

extern "C" void kernel_launch(void* const* d_in, const int* in_sizes, int n_in,
                              void* d_out, int out_size, void* d_ws, size_t ws_size,
                              hipStream_t stream) {
  const float* xyz = (const float*)d_in[0];
  float* out = (float*)d_out;
  fps_kernel<<<dim3(BB), dim3(1024), 0, stream>>>(xyz, out);
  knn_kernel<<<dim3(BB * 8), dim3(512), 0, stream>>>(xyz, out);
}

// Round 3
// 411.043 us; speedup vs baseline: 1.0633x; 1.0633x over previous
//
#include <hip/hip_runtime.h>

#pragma clang fp contract(off)

#define BB 32
#define NN 8192
#define GG 256
#define KK 32

#define TFPS 256
#define JP (NN / TFPS)  // 32 points per thread

// DPP row_ror<N> based max-reduce step on a (hi,lo) u64 key.
// row_ror rotates within each 16-lane row; rotations by 1,2,4,8 give every
// lane the max over its full 16-lane row (pure VALU, no LDS/bpermute).
template <int CTRL>
__device__ __forceinline__ void rot_max(unsigned& hi, unsigned& lo) {
  const unsigned ohi =
      (unsigned)__builtin_amdgcn_update_dpp(0, (int)hi, CTRL, 0xF, 0xF, true);
  const unsigned olo =
      (unsigned)__builtin_amdgcn_update_dpp(0, (int)lo, CTRL, 0xF, 0xF, true);
  const bool gt = (ohi > hi) || ((ohi == hi) && (olo > lo));
  hi = gt ? ohi : hi;
  lo = gt ? olo : lo;
}

// ---------------- FPS: one block per batch, 256 threads ----------------
__global__ __launch_bounds__(TFPS, 1) void fps_kernel(const float* __restrict__ xyz,
                                                      float* __restrict__ out) {
#pragma clang fp contract(off)
  const int b = blockIdx.x;
  const int t = threadIdx.x;
  const int lane = t & 63;
  const int wave = t >> 6;
  const float* __restrict__ P = xyz + (size_t)b * NN * 3;

  __shared__ float xs[NN], ys[NN], zs[NN];            // 96 KB SoA copy
  __shared__ unsigned long long warr[2][16];

  float px[JP], py[JP], pz[JP], md[JP];
#pragma unroll
  for (int j = 0; j < JP; ++j) {
    const int idx = t + j * TFPS;
    const float x = P[idx * 3 + 0];
    const float y = P[idx * 3 + 1];
    const float z = P[idx * 3 + 2];
    px[j] = x; py[j] = y; pz[j] = z;
    md[j] = __builtin_inff();
    xs[idx] = x; ys[idx] = y; zs[idx] = z;
  }
  __syncthreads();

  unsigned win = 0;      // first center = index 0
  unsigned mywin = 0;    // thread t records the step-t winner (GG == TFPS)

  for (int i = 0; i < GG; ++i) {
    if (i == t) mywin = win;
    if (i == GG - 1) break;

    // broadcast winner coords from LDS (no global access in the loop)
    const float cx = xs[win];
    const float cy = ys[win];
    const float cz = zs[win];

    // distance update + 4 parallel argmax chains (tie -> lowest index)
    float bv0 = -1.0f, bv1 = -1.0f, bv2 = -1.0f, bv3 = -1.0f;
    unsigned bi0 = 0, bi1 = 0, bi2 = 0, bi3 = 0;
#pragma unroll
    for (int j = 0; j < JP; j += 4) {
#pragma unroll
      for (int c = 0; c < 4; ++c) {
        const int jj = j + c;
        const float dx = px[jj] - cx;
        const float dy = py[jj] - cy;
        const float dz = pz[jj] - cz;
        const float d = dx * dx + dy * dy + dz * dz;  // ((x2+y2)+z2), no FMA
        const float m = md[jj] < d ? md[jj] : d;
        md[jj] = m;
        const unsigned idx = (unsigned)(t + jj * TFPS);
        if (c == 0) { if (m > bv0) { bv0 = m; bi0 = idx; } }
        else if (c == 1) { if (m > bv1) { bv1 = m; bi1 = idx; } }
        else if (c == 2) { if (m > bv2) { bv2 = m; bi2 = idx; } }
        else { if (m > bv3) { bv3 = m; bi3 = idx; } }
      }
    }
    // merge chains; ties -> smaller index
    if (bv1 > bv0 || (bv1 == bv0 && bi1 < bi0)) { bv0 = bv1; bi0 = bi1; }
    if (bv3 > bv2 || (bv3 == bv2 && bi3 < bi2)) { bv2 = bv3; bi2 = bi3; }
    if (bv2 > bv0 || (bv2 == bv0 && bi2 < bi0)) { bv0 = bv2; bi0 = bi2; }

    // 16-lane row argmax via DPP rotations (key: value bits, ~idx)
    unsigned hi = __float_as_uint(bv0);
    unsigned lo = ~bi0;
    rot_max<0x121>(hi, lo);  // ror 1
    rot_max<0x122>(hi, lo);  // ror 2
    rot_max<0x124>(hi, lo);  // ror 4
    rot_max<0x128>(hi, lo);  // ror 8

    // one row-max per 16 lanes -> 16 entries total (4 waves x 4 rows)
    if ((lane & 15) == 0)
      warr[i & 1][wave * 4 + (lane >> 4)] =
          ((unsigned long long)hi << 32) | lo;
    __syncthreads();

    // every lane reads one of the 16 entries, 4 DPP stages -> global max
    const unsigned long long k = warr[i & 1][lane & 15];
    hi = (unsigned)(k >> 32);
    lo = (unsigned)k;
    rot_max<0x121>(hi, lo);
    rot_max<0x122>(hi, lo);
    rot_max<0x124>(hi, lo);
    rot_max<0x128>(hi, lo);

    win = ~lo;
  }

  // write all centers once (coalesced-ish, off the critical loop)
  float* __restrict__ co = out + (size_t)BB * GG * KK * 3 + ((size_t)b * GG + t) * 3;
  co[0] = xs[mywin];
  co[1] = ys[mywin];
  co[2] = zs[mywin];
}

// ---------------- KNN + gather: 8 blocks per batch ----------------
__global__ __launch_bounds__(512, 1) void knn_kernel(const float* __restrict__ xyz,
                                                     float* __restrict__ out) {
#pragma clang fp contract(off)
  const int b = blockIdx.x >> 3;
  const int chunk = blockIdx.x & 7;
  const int t = threadIdx.x;
  const int lane = t & 63;
  const int wave = t >> 6;
  const float* __restrict__ P = xyz + (size_t)b * NN * 3;

  __shared__ float4 pts4[NN];                   // 128 KB, b128 reads
  __shared__ unsigned long long cand[8][256];   // 16 KB per-wave candidates

  for (int pt = t; pt < NN; pt += 512) {
    pts4[pt] = make_float4(P[pt * 3 + 0], P[pt * 3 + 1], P[pt * 3 + 2], 0.0f);
  }
  __syncthreads();

  const float* __restrict__ cent = out + (size_t)BB * GG * KK * 3;

  for (int gi = 0; gi < 4; ++gi) {
    const int g = chunk * 32 + wave * 4 + gi;
    const float cx = cent[((size_t)b * GG + g) * 3 + 0];
    const float cy = cent[((size_t)b * GG + g) * 3 + 1];
    const float cz = cent[((size_t)b * GG + g) * 3 + 2];

    // Phase A: 128 squared distances per lane, kept in registers
    float d2r[128];
    float mn = __builtin_inff();
#pragma unroll
    for (int j = 0; j < 128; ++j) {
      const int idx = lane + j * 64;
      const float4 p = pts4[idx];
      const float dx = p.x - cx;
      const float dy = p.y - cy;
      const float dz = p.z - cz;
      const float d2 = dx * dx + dy * dy + dz * dz;  // no FMA
      d2r[j] = d2;
      mn = fminf(mn, d2);
    }

    // threshold v = 32nd-smallest of the 64 per-lane minima (bitonic sort)
    float sm = mn;
#pragma unroll
    for (int k = 2; k <= 64; k <<= 1) {
#pragma unroll
      for (int j2 = k >> 1; j2 > 0; j2 >>= 1) {
        const float o = __shfl_xor(sm, j2, 64);
        const bool keepMin = (((lane & k) == 0) == ((lane & j2) == 0));
        sm = keepMin ? fminf(sm, o) : fmaxf(sm, o);
      }
    }
    const float v = __shfl(sm, 31, 64);
    const float vi = __uint_as_float(__float_as_uint(v) + 8);  // +8 ulp guard

    // Phase B: ballot-compact candidates (d2 <= vi) into LDS
    unsigned cnt = 0;
    unsigned long long* __restrict__ cb = cand[wave];
#pragma unroll
    for (int j = 0; j < 128; ++j) {
      const bool p = d2r[j] <= vi;
      const unsigned long long mk = __ballot(p);
      if (p) {
        const unsigned off = cnt + (unsigned)__popcll(mk & ((1ull << lane) - 1));
        if (off < 256)
          cb[off] = ((unsigned long long)__float_as_uint(d2r[j]) << 32) |
                    (unsigned)(lane + j * 64);
      }
      cnt += (unsigned)__popcll(mk);
    }
    if (cnt > 256) cnt = 256;

    // Phase C: exact sort by (sqrtf(d2) float, idx) ascending
    auto conv = [](unsigned long long e) -> unsigned long long {
      const float d = sqrtf(__uint_as_float((unsigned)(e >> 32)));
      return ((unsigned long long)__float_as_uint(d) << 32) | (e & 0xFFFFFFFFull);
    };

    unsigned long long myk;
    if (cnt <= 64) {
      unsigned long long key = ~0ull;
      if ((unsigned)lane < cnt) key = conv(cb[lane]);
#pragma unroll
      for (int k = 2; k <= 64; k <<= 1) {
#pragma unroll
        for (int j2 = k >> 1; j2 > 0; j2 >>= 1) {
          const unsigned long long o = __shfl_xor(key, j2, 64);
          const bool keepMin = (((lane & k) == 0) == ((lane & j2) == 0));
          const unsigned long long lo = o < key ? o : key;
          const unsigned long long hi = o < key ? key : o;
          key = keepMin ? lo : hi;
        }
      }
      myk = key;
    } else {
      // rare fallback: up to 256 candidates, 32 rounds of wave-argmin
      unsigned long long k0 = ~0ull, k1 = ~0ull, k2 = ~0ull, k3 = ~0ull;
      if ((unsigned)lane < cnt)         k0 = conv(cb[lane]);
      if ((unsigned)(lane + 64) < cnt)  k1 = conv(cb[lane + 64]);
      if ((unsigned)(lane + 128) < cnt) k2 = conv(cb[lane + 128]);
      if ((unsigned)(lane + 192) < cnt) k3 = conv(cb[lane + 192]);
      unsigned long long got = ~0ull;
      for (int r = 0; r < 32; ++r) {
        unsigned long long m01 = k0 < k1 ? k0 : k1;
        unsigned long long m23 = k2 < k3 ? k2 : k3;
        unsigned long long m = m01 < m23 ? m01 : m23;
#pragma unroll
        for (int s = 32; s > 0; s >>= 1) {
          const unsigned long long o = __shfl_xor(m, s, 64);
          m = o < m ? o : m;
        }
        if (lane == r) got = m;
        if (k0 == m) k0 = ~0ull;
        else if (k1 == m) k1 = ~0ull;
        else if (k2 == m) k2 = ~0ull;
        else if (k3 == m) k3 = ~0ull;
      }
      myk = got;
    }

    // gather + recenter + store (lane = rank)
    if (lane < KK) {
      const unsigned idx = (unsigned)(myk & 0xFFFFFFFFull);
      const float4 p = pts4[idx];
      const float ox = p.x - cx;
      const float oy = p.y - cy;
      const float oz = p.z - cz;
      float* __restrict__ po = out + ((size_t)(((size_t)b * GG + g) * KK + lane)) * 3;
      po[0] = ox; po[1] = oy; po[2] = oz;
    }
  }
}

extern "C" void kernel_launch(void* const* d_in, const int* in_sizes, int n_in,
                              void* d_out, int out_size, void* d_ws, size_t ws_size,
                              hipStream_t stream) {
  const float* xyz = (const float*)d_in[0];
  float* out = (float*)d_out;
  fps_kernel<<<dim3(BB), dim3(TFPS), 0, stream>>>(xyz, out);
  knn_kernel<<<dim3(BB * 8), dim3(512), 0, stream>>>(xyz, out);
}

// Round 4
// 362.328 us; speedup vs baseline: 1.2063x; 1.1345x over previous
//
#include <hip/hip_runtime.h>

#pragma clang fp contract(off)

#define BB 32
#define NN 8192
#define GG 256
#define KK 32

#define TFPS 512
#define JPF (NN / TFPS)  // 16 points per thread

// DPP row_ror<N> based max-reduce step on a (hi,lo) u64 key.
// row_ror rotates within each 16-lane row; rotations by 1,2,4,8 give every
// lane the max over its full 16-lane row (pure VALU, no LDS/bpermute).
template <int CTRL>
__device__ __forceinline__ void rot_max(unsigned& hi, unsigned& lo) {
  const unsigned ohi =
      (unsigned)__builtin_amdgcn_update_dpp(0, (int)hi, CTRL, 0xF, 0xF, true);
  const unsigned olo =
      (unsigned)__builtin_amdgcn_update_dpp(0, (int)lo, CTRL, 0xF, 0xF, true);
  const bool gt = (ohi > hi) || ((ohi == hi) && (olo > lo));
  hi = gt ? ohi : hi;
  lo = gt ? olo : lo;
}

// ---------------- FPS: one block per batch, 512 threads ----------------
__global__ __launch_bounds__(TFPS, 1) void fps_kernel(const float* __restrict__ xyz,
                                                      float* __restrict__ out) {
#pragma clang fp contract(off)
  const int b = blockIdx.x;
  const int t = threadIdx.x;
  const int lane = t & 63;
  const int wave = t >> 6;  // 0..7
  const float* __restrict__ P = xyz + (size_t)b * NN * 3;

  __shared__ float4 pts[NN];                 // 128 KB: 1 ds_read_b128 / bcast
  __shared__ unsigned long long warr[2][32]; // 8 waves x 4 rows, dbuf

  float px[JPF], py[JPF], pz[JPF], md[JPF];
#pragma unroll
  for (int j = 0; j < JPF; ++j) {
    const int idx = t + j * TFPS;
    const float x = P[idx * 3 + 0];
    const float y = P[idx * 3 + 1];
    const float z = P[idx * 3 + 2];
    px[j] = x; py[j] = y; pz[j] = z;
    md[j] = __builtin_inff();
    pts[idx] = make_float4(x, y, z, 0.0f);
  }
  __syncthreads();

  unsigned win = 0;      // first center = index 0
  unsigned mywin = 0;    // thread t<GG records the step-t winner

  for (int i = 0; i < GG; ++i) {
    if (t == i) mywin = win;
    if (i == GG - 1) break;

    // broadcast winner coords from LDS (single b128, uniform address)
    const float4 c = pts[win];
    const float cx = c.x, cy = c.y, cz = c.z;

    // distance update + 2 parallel argmax chains (tie -> lowest index)
    float bv0 = -1.0f, bv1 = -1.0f;
    unsigned bi0 = 0, bi1 = 0;
#pragma unroll
    for (int j = 0; j < JPF; j += 2) {
      {
        const float dx = px[j] - cx;
        const float dy = py[j] - cy;
        const float dz = pz[j] - cz;
        const float d = dx * dx + dy * dy + dz * dz;  // ((x2+y2)+z2), no FMA
        const float m = md[j] < d ? md[j] : d;
        md[j] = m;
        if (m > bv0) { bv0 = m; bi0 = (unsigned)(t + j * TFPS); }
      }
      {
        const int jj = j + 1;
        const float dx = px[jj] - cx;
        const float dy = py[jj] - cy;
        const float dz = pz[jj] - cz;
        const float d = dx * dx + dy * dy + dz * dz;
        const float m = md[jj] < d ? md[jj] : d;
        md[jj] = m;
        if (m > bv1) { bv1 = m; bi1 = (unsigned)(t + jj * TFPS); }
      }
    }
    // merge chains; ties -> smaller index
    if (bv1 > bv0 || (bv1 == bv0 && bi1 < bi0)) { bv0 = bv1; bi0 = bi1; }

    // level 1: 16-lane row argmax via DPP rotations (key: value bits, ~idx)
    unsigned hi = __float_as_uint(bv0);
    unsigned lo = ~bi0;
    rot_max<0x121>(hi, lo);  // ror 1
    rot_max<0x122>(hi, lo);  // ror 2
    rot_max<0x124>(hi, lo);  // ror 4
    rot_max<0x128>(hi, lo);  // ror 8

    // one row-max per 16 lanes -> 32 entries (8 waves x 4 rows)
    if ((lane & 15) == 0)
      warr[i & 1][wave * 4 + (lane >> 4)] =
          ((unsigned long long)hi << 32) | lo;
    __syncthreads();

    // level 2: each lane merges 2 of the 32 entries, then 4 DPP stages
    const int g = lane & 15;
    const unsigned long long kA = warr[i & 1][g];
    const unsigned long long kB = warr[i & 1][g + 16];
    const unsigned long long k = kB > kA ? kB : kA;
    hi = (unsigned)(k >> 32);
    lo = (unsigned)k;
    rot_max<0x121>(hi, lo);
    rot_max<0x122>(hi, lo);
    rot_max<0x124>(hi, lo);
    rot_max<0x128>(hi, lo);

    win = ~lo;
  }

  // write all centers once (off the critical loop)
  if (t < GG) {
    const float4 c = pts[mywin];
    float* __restrict__ co =
        out + (size_t)BB * GG * KK * 3 + ((size_t)b * GG + t) * 3;
    co[0] = c.x; co[1] = c.y; co[2] = c.z;
  }
}

// ---------------- KNN + gather: 8 blocks per batch ----------------
__global__ __launch_bounds__(512, 1) void knn_kernel(const float* __restrict__ xyz,
                                                     float* __restrict__ out) {
#pragma clang fp contract(off)
  const int b = blockIdx.x >> 3;
  const int chunk = blockIdx.x & 7;
  const int t = threadIdx.x;
  const int lane = t & 63;
  const int wave = t >> 6;
  const float* __restrict__ P = xyz + (size_t)b * NN * 3;

  __shared__ float xs[NN], ys[NN], zs[NN];          // 96 KB SoA planes
  __shared__ unsigned long long cand[8][256];       // 16 KB per-wave candidates

  for (int pt = t; pt < NN; pt += 512) {
    xs[pt] = P[pt * 3 + 0];
    ys[pt] = P[pt * 3 + 1];
    zs[pt] = P[pt * 3 + 2];
  }
  __syncthreads();

  const float* __restrict__ cent = out + (size_t)BB * GG * KK * 3;

  for (int gi = 0; gi < 4; ++gi) {
    const int g = chunk * 32 + wave * 4 + gi;
    const float cx = cent[((size_t)b * GG + g) * 3 + 0];
    const float cy = cent[((size_t)b * GG + g) * 3 + 1];
    const float cz = cent[((size_t)b * GG + g) * 3 + 2];

    // Phase A: 128 squared distances per lane, kept in registers
    float d2r[128];
    float mn = __builtin_inff();
#pragma unroll
    for (int j = 0; j < 128; ++j) {
      const int idx = lane + j * 64;
      const float dx = xs[idx] - cx;
      const float dy = ys[idx] - cy;
      const float dz = zs[idx] - cz;
      const float d2 = dx * dx + dy * dy + dz * dz;  // no FMA
      d2r[j] = d2;
      mn = fminf(mn, d2);
    }

    // threshold v = 32nd-smallest of the 64 per-lane minima (bitonic sort)
    float sm = mn;
#pragma unroll
    for (int k = 2; k <= 64; k <<= 1) {
#pragma unroll
      for (int j2 = k >> 1; j2 > 0; j2 >>= 1) {
        const float o = __shfl_xor(sm, j2, 64);
        const bool keepMin = (((lane & k) == 0) == ((lane & j2) == 0));
        sm = keepMin ? fminf(sm, o) : fmaxf(sm, o);
      }
    }
    const float v = __shfl(sm, 31, 64);
    const float vi = __uint_as_float(__float_as_uint(v) + 8);  // +8 ulp guard

    // Phase B: ballot-compact candidates (d2 <= vi) into LDS
    unsigned cnt = 0;
    unsigned long long* __restrict__ cb = cand[wave];
#pragma unroll
    for (int j = 0; j < 128; ++j) {
      const bool p = d2r[j] <= vi;
      const unsigned long long mk = __ballot(p);
      if (p) {
        const unsigned off = cnt + (unsigned)__popcll(mk & ((1ull << lane) - 1));
        if (off < 256)
          cb[off] = ((unsigned long long)__float_as_uint(d2r[j]) << 32) |
                    (unsigned)(lane + j * 64);
      }
      cnt += (unsigned)__popcll(mk);
    }
    if (cnt > 256) cnt = 256;

    // Phase C: exact sort by (sqrtf(d2) float, idx) ascending
    auto conv = [](unsigned long long e) -> unsigned long long {
      const float d = sqrtf(__uint_as_float((unsigned)(e >> 32)));
      return ((unsigned long long)__float_as_uint(d) << 32) | (e & 0xFFFFFFFFull);
    };

    unsigned long long myk;
    if (cnt <= 64) {
      unsigned long long key = ~0ull;
      if ((unsigned)lane < cnt) key = conv(cb[lane]);
#pragma unroll
      for (int k = 2; k <= 64; k <<= 1) {
#pragma unroll
        for (int j2 = k >> 1; j2 > 0; j2 >>= 1) {
          const unsigned long long o = __shfl_xor(key, j2, 64);
          const bool keepMin = (((lane & k) == 0) == ((lane & j2) == 0));
          const unsigned long long lo = o < key ? o : key;
          const unsigned long long hi = o < key ? key : o;
          key = keepMin ? lo : hi;
        }
      }
      myk = key;
    } else {
      // rare fallback: up to 256 candidates, 32 rounds of wave-argmin
      unsigned long long k0 = ~0ull, k1 = ~0ull, k2 = ~0ull, k3 = ~0ull;
      if ((unsigned)lane < cnt)         k0 = conv(cb[lane]);
      if ((unsigned)(lane + 64) < cnt)  k1 = conv(cb[lane + 64]);
      if ((unsigned)(lane + 128) < cnt) k2 = conv(cb[lane + 128]);
      if ((unsigned)(lane + 192) < cnt) k3 = conv(cb[lane + 192]);
      unsigned long long got = ~0ull;
      for (int r = 0; r < 32; ++r) {
        unsigned long long m01 = k0 < k1 ? k0 : k1;
        unsigned long long m23 = k2 < k3 ? k2 : k3;
        unsigned long long m = m01 < m23 ? m01 : m23;
#pragma unroll
        for (int s = 32; s > 0; s >>= 1) {
          const unsigned long long o = __shfl_xor(m, s, 64);
          m = o < m ? o : m;
        }
        if (lane == r) got = m;
        if (k0 == m) k0 = ~0ull;
        else if (k1 == m) k1 = ~0ull;
        else if (k2 == m) k2 = ~0ull;
        else if (k3 == m) k3 = ~0ull;
      }
      myk = got;
    }

    // gather + recenter + store (lane = rank)
    if (lane < KK) {
      const unsigned idx = (unsigned)(myk & 0xFFFFFFFFull);
      const float ox = xs[idx] - cx;
      const float oy = ys[idx] - cy;
      const float oz = zs[idx] - cz;
      float* __restrict__ po = out + ((size_t)(((size_t)b * GG + g) * KK + lane)) * 3;
      po[0] = ox; po[1] = oy; po[2] = oz;
    }
  }
}

extern "C" void kernel_launch(void* const* d_in, const int* in_sizes, int n_in,
                              void* d_out, int out_size, void* d_ws, size_t ws_size,
                              hipStream_t stream) {
  const float* xyz = (const float*)d_in[0];
  float* out = (float*)d_out;
  fps_kernel<<<dim3(BB), dim3(TFPS), 0, stream>>>(xyz, out);
  knn_kernel<<<dim3(BB * 8), dim3(512), 0, stream>>>(xyz, out);
}